// Round 20
// baseline (219.471 us; speedup 1.0000x reference)
//
#include <hip/hip_runtime.h>
#include <hip/hip_bf16.h>

// Problem constants (fixed by reference): B=4, S=2048, DIN=DOUT=4096
constexpr int GM = 8192;   // B*S rows
constexpr int GN = 4096;   // DOUT
constexpr int GK = 4096;   // DIN

constexpr int BM = 256, BN = 256, BK = 64;    // BK in i8 elements (= bytes)
constexpr int NSTEP = GK / BK;                // 64 K-steps
constexpr int SLOT_BYTES = (BM + BN) * BK;    // 32768 (A 16K + B 16K, i8)
constexpr int LDS_BYTES = 2 * SLOT_BYTES;     // 65536

constexpr int PX_BLOCKS = GM;                          // 8192 (1 block/row)
constexpr int PW_BLOCKS = (GN * GK) / (256 * 8);       // 8192

using bf16x8 = __attribute__((ext_vector_type(8))) __bf16;
using i32x4  = __attribute__((ext_vector_type(4))) int;
using i32x16 = __attribute__((ext_vector_type(16))) int;

// ---- fused prep: rows -> per-row absmax i8 quantize; tail -> sign(w) i8 ----
__global__ __launch_bounds__(256) void prep_fused_i8(
    const float* __restrict__ x, const float* __restrict__ iscale,
    const float* __restrict__ w, signed char* __restrict__ A,
    signed char* __restrict__ Wb, float* __restrict__ alpha) {
  int b = blockIdx.x;
  int t = threadIdx.x;
  if (b < PX_BLOCKS) {
    // prep_x: one block per row; alpha[row] = rowmax/127; A = rint(x*s/alpha)
    int row = b;
    const float* xr = x + (size_t)row * GK;
    float v[16];
    float mx = 0.f;
#pragma unroll
    for (int p = 0; p < 4; ++p) {
      int idx = p * 1024 + t * 4;
      float4 xv = *(const float4*)(xr + idx);
      float4 sv = *(const float4*)(iscale + idx);
      float a0 = xv.x * sv.x, a1 = xv.y * sv.y, a2 = xv.z * sv.z, a3 = xv.w * sv.w;
      v[p * 4 + 0] = a0; v[p * 4 + 1] = a1; v[p * 4 + 2] = a2; v[p * 4 + 3] = a3;
      mx = fmaxf(mx, fmaxf(fmaxf(fabsf(a0), fabsf(a1)), fmaxf(fabsf(a2), fabsf(a3))));
    }
#pragma unroll
    for (int off = 32; off > 0; off >>= 1)
      mx = fmaxf(mx, __shfl_down(mx, off));
    __shared__ float rm[4];
    int wid = t >> 6, lane = t & 63;
    if (lane == 0) rm[wid] = mx;
    __syncthreads();
    float m = fmaxf(fmaxf(rm[0], rm[1]), fmaxf(rm[2], rm[3]));
    float inv = m > 0.f ? 127.f / m : 0.f;
    if (t == 0) alpha[row] = m * (1.f / 127.f);
#pragma unroll
    for (int p = 0; p < 4; ++p) {
      int idx = p * 1024 + t * 4;
      char4 q;
      int q0 = (int)rintf(v[p * 4 + 0] * inv);
      int q1 = (int)rintf(v[p * 4 + 1] * inv);
      int q2 = (int)rintf(v[p * 4 + 2] * inv);
      int q3 = (int)rintf(v[p * 4 + 3] * inv);
      q.x = (signed char)max(-127, min(127, q0));
      q.y = (signed char)max(-127, min(127, q1));
      q.z = (signed char)max(-127, min(127, q2));
      q.w = (signed char)max(-127, min(127, q3));
      *(char4*)(A + (size_t)row * GK + idx) = q;
    }
  } else {
    // prep_w: sign(w) in {-1,0,+1}, exact
    int e = ((b - PX_BLOCKS) * 256 + t) * 8;
    float4 v0 = *(const float4*)(w + e);
    float4 v1 = *(const float4*)(w + e + 4);
    auto sg = [](float v) -> signed char {
      return (signed char)((v > 0.f) - (v < 0.f));
    };
    union { signed char c[8]; unsigned long long u; } o;
    o.c[0] = sg(v0.x); o.c[1] = sg(v0.y); o.c[2] = sg(v0.z); o.c[3] = sg(v0.w);
    o.c[4] = sg(v1.x); o.c[5] = sg(v1.y); o.c[6] = sg(v1.z); o.c[7] = sg(v1.w);
    *(unsigned long long*)(Wb + e) = o.u;
  }
}

// -------------------- GEMM (i8, 32x32x32): C = alpha_m * qA·sgnW^T --------------------
// R19's zero-asm m97-shaped loop, MFMA shape 16x16x64 -> 32x32x32:
//   +11.7% MFMA-pipe rate (4404 vs 3944 TOPS measured) and HALF the MFMA
//   instructions per K-step (16 x 65536-OP vs 32 x 32768-OP per wave) ->
//   half the issue slots and lgkm-wait boundaries in the serialized region.
// Bank safety (the R10 32x32 regression, explained): with 128-B rows the
// bank index (r*128+c*16)/4 %32 = 4c — row drops out, so chunk-XOR can't
// spread lanes. With i8's 64-B rows, bank = 16*(r&1) + 4*(hi^((r>>1)&3)):
// a wave's b128 read spreads 64 lanes exactly 8 per 16-B bank-group = the
// 8-cycle minimum, zero excess conflict (predicted counter ~0; if >1e7
// the theory is wrong -> revert).
// Fragment mapping (on-device verified by R10's passing 32x32 bf16 run):
// A: row=l&31, k=hi*16+e (+32s per slice s); B: col=l&31, same k;
// C/D: col=lane&31, row=(reg&3)+8*(reg>>2)+4*hi.
// Loop per K-step (one barrier, plain C++ reads, compiler counted-lgkm):
//   { STAGE(t+1 -> buf^1); 12 b128 reads (af[8],bf[4]); 16 MFMA;
//     __syncthreads(); }
// Swizzle identical to R17-R19 (0 conflicts, absmax 0.1035): 16-B chunk c
// of row r holds k-group c^((r>>1)&3), both sides.
__device__ inline void gload16(const void* g, const void* l) {
  __builtin_amdgcn_global_load_lds(
      (const __attribute__((address_space(1))) void*)g,
      (__attribute__((address_space(3))) void*)l, 16, 0, 0);
}

__global__ __launch_bounds__(512, 2) void gemm_i8(
    const signed char* __restrict__ A, const signed char* __restrict__ Bm,
    const float* __restrict__ alpha, float* __restrict__ C) {
  extern __shared__ signed char lds8[];  // 2 slots x (A 16K + B 16K)

  // Square XCD chunking (R3-R19; FETCH ~98 MB on i8)
  int bid = blockIdx.x;            // 0..511
  int x = bid & 7, idx = bid >> 3;
  int brow = ((x & 3) << 3) | (idx & 7);   // 0..31
  int bcol = ((x >> 2) << 3) | (idx >> 3); // 0..15

  int tid = threadIdx.x, wid = tid >> 6, lane = tid & 63;
  int wm = wid & 1, wn = wid >> 1;         // 2M x 4N waves, wave tile 128x64
  int l31 = lane & 31, hi = lane >> 5;

  const signed char* Ab = A + (size_t)(brow * BM) * GK;
  const signed char* Bb = Bm + (size_t)(bcol * BN) * GK;

  // read-side swizzled chunk offsets per k-slice (4 x 16-B chunks / 64-B row)
  int xr = (lane >> 1) & 3;                // == (row>>1)&3 for row = l&31
  int offk0 = ((0 + hi) ^ xr) * 16;        // slice 0: k 0..31
  int offk1 = ((2 + hi) ^ xr) * 16;        // slice 1: k 32..63
  // fragment byte bases within a slot (A at 0, B at 16 KiB); + mi/ni * 2048
  int avbase = (wm * 128 + l31) * 64;
  int bvbase = 16384 + (wn * 64 + l31) * 64;

  // stage-side: thread t covers row t>>2 (0..127), chunk t&3; source chunk
  // pre-permuted so LDS chunk c of row r holds k-group c^((r>>1)&3).
  // Row+128 (2nd issue) preserves (r>>1)&3, so the same gcol applies.
  int grow = tid >> 2;
  int gcol = ((tid & 3) ^ ((tid >> 3) & 3)) * 16;  // byte offset in 64-B window

  auto STAGE = [&](int kstep, int si) {
    const signed char* sA = Ab + (size_t)grow * GK + kstep * BK + gcol;
    const signed char* dA = lds8 + si * SLOT_BYTES + tid * 16;
    gload16(sA, dA);
    gload16(sA + (size_t)128 * GK, dA + 8192);
    const signed char* sB = Bb + (size_t)grow * GK + kstep * BK + gcol;
    gload16(sB, dA + 16384);
    gload16(sB + (size_t)128 * GK, dA + 16384 + 8192);
  };

  i32x16 acc[4][2] = {};

  // prologue: step 0 -> slot 0 (syncthreads drains vmcnt before the barrier)
  STAGE(0, 0);
  __syncthreads();

  for (int t = 0; t < NSTEP; ++t) {
    const signed char* sl = lds8 + (t & 1) * SLOT_BYTES;
    if (t + 1 < NSTEP) STAGE(t + 1, (t + 1) & 1);

    // plain C++ LDS reads — compiler emits counted lgkmcnt and interleaves
    // the MFMAs below with the in-flight reads. af[s*4+mi], bf[s*2+ni].
    i32x4 af[8], bf[4];
#pragma unroll
    for (int mi = 0; mi < 4; ++mi) {
      af[mi]     = *(const i32x4*)(sl + avbase + mi * 2048 + offk0);
      af[4 + mi] = *(const i32x4*)(sl + avbase + mi * 2048 + offk1);
    }
#pragma unroll
    for (int ni = 0; ni < 2; ++ni) {
      bf[ni]     = *(const i32x4*)(sl + bvbase + ni * 2048 + offk0);
      bf[2 + ni] = *(const i32x4*)(sl + bvbase + ni * 2048 + offk1);
    }

#pragma unroll
    for (int s = 0; s < 2; ++s)
#pragma unroll
      for (int mi = 0; mi < 4; ++mi)
#pragma unroll
        for (int ni = 0; ni < 2; ++ni)
          acc[mi][ni] = __builtin_amdgcn_mfma_i32_32x32x32_i8(
              af[s * 4 + mi], bf[s * 2 + ni], acc[mi][ni], 0, 0, 0);

    // one barrier per K-step: makes STAGE(t+1) visible for step t+1 and
    // orders this step's reads before STAGE(t+2)'s overwrite (WAR).
    __syncthreads();
  }

  // epilogue: h = alpha[row]*acc as bf16 into 2nd half of each f32 row slot.
  // C/D 32x32: col = lane&31, row = (reg&3) + 8*(reg>>2) + 4*hi
  int crow0 = brow * BM + wm * 128 + hi * 4;
  int ccol0 = bcol * BN + wn * 64;
  char* Cb = (char*)C;
#pragma unroll
  for (int mi = 0; mi < 4; ++mi)
#pragma unroll
    for (int ni = 0; ni < 2; ++ni) {
      int col = ccol0 + ni * 32 + l31;
#pragma unroll
      for (int r = 0; r < 16; ++r) {
        int row = crow0 + mi * 32 + (r & 3) + 8 * (r >> 2);
        float h = alpha[row] * (float)acc[mi][ni][r];
        *(__bf16*)(Cb + (size_t)row * 16384 + 8192 + col * 2) = (__bf16)h;
      }
    }
}

// ---------- fused out_scale/bias + LayerNorm: bf16 h (2nd half-slot) -> f32 ----------
__global__ __launch_bounds__(256) void ln_fuse(
    float* __restrict__ out, const float* __restrict__ os,
    const float* __restrict__ bs, const float* __restrict__ g,
    const float* __restrict__ be) {
  constexpr int N = GN;  // 4096
  int row = blockIdx.x;
  const __bf16* hr = (const __bf16*)((const char*)out + (size_t)row * 16384 + 8192);
  float* orow = out + (size_t)row * N;
  int t = threadIdx.x;

  float v[16];
  float sum = 0.f, ssq = 0.f;
#pragma unroll
  for (int c = 0; c < 2; ++c) {
    int idx = c * 2048 + t * 8;       // 8 bf16 per chunk, 2 chunks/thread
    bf16x8 hv = *(const bf16x8*)(hr + idx);
    float4 s0 = *(const float4*)(os + idx);
    float4 s1 = *(const float4*)(os + idx + 4);
    float4 b0 = *(const float4*)(bs + idx);
    float4 b1 = *(const float4*)(bs + idx + 4);
#pragma unroll
    for (int j = 0; j < 4; ++j) {
      float a = (float)hv[j] * (&s0.x)[j] + (&b0.x)[j];
      v[c * 8 + j] = a;
      sum += a; ssq += a * a;
    }
#pragma unroll
    for (int j = 0; j < 4; ++j) {
      float a = (float)hv[4 + j] * (&s1.x)[j] + (&b1.x)[j];
      v[c * 8 + 4 + j] = a;
      sum += a; ssq += a * a;
    }
  }

  // wave64 reduce
#pragma unroll
  for (int off = 32; off > 0; off >>= 1) {
    sum += __shfl_down(sum, off);
    ssq += __shfl_down(ssq, off);
  }
  __shared__ float rs[8];
  int wid = t >> 6, lane = t & 63;
  if (lane == 0) { rs[wid] = sum; rs[4 + wid] = ssq; }
  __syncthreads();   // also separates all h reads from the in-place writes
  sum = rs[0] + rs[1] + rs[2] + rs[3];
  ssq = rs[4] + rs[5] + rs[6] + rs[7];

  float mean = sum * (1.f / N);
  float var = ssq * (1.f / N) - mean * mean;
  float rstd = rsqrtf(var + 1e-5f);

#pragma unroll
  for (int c = 0; c < 2; ++c) {
    int idx = c * 2048 + t * 8;
    float4 g0 = *(const float4*)(g + idx);
    float4 g1 = *(const float4*)(g + idx + 4);
    float4 e0 = *(const float4*)(be + idx);
    float4 e1 = *(const float4*)(be + idx + 4);
    float4 o0, o1;
#pragma unroll
    for (int j = 0; j < 4; ++j) {
      (&o0.x)[j] = (v[c * 8 + j] - mean) * rstd * (&g0.x)[j] + (&e0.x)[j];
      (&o1.x)[j] = (v[c * 8 + 4 + j] - mean) * rstd * (&g1.x)[j] + (&e1.x)[j];
    }
    *(float4*)(orow + idx) = o0;
    *(float4*)(orow + idx + 4) = o1;
  }
}

extern "C" void kernel_launch(void* const* d_in, const int* in_sizes, int n_in,
                              void* d_out, int out_size, void* d_ws, size_t ws_size,
                              hipStream_t stream) {
  const float* x      = (const float*)d_in[0];  // [4,2048,4096]
  const float* w      = (const float*)d_in[1];  // [4096,4096]
  const float* iscale = (const float*)d_in[2];  // [4096]
  const float* oscale = (const float*)d_in[3];  // [4096]
  const float* bias   = (const float*)d_in[4];  // [4096]
  const float* gamma  = (const float*)d_in[5];  // [4096]
  const float* beta   = (const float*)d_in[6];  // [4096]
  float* out = (float*)d_out;                   // [8192,4096] f32

  signed char* Ai8 = (signed char*)d_ws;                         // 33.6 MB
  signed char* Wi8 = (signed char*)d_ws + (size_t)GM * GK;       // 16.8 MB
  float* alpha = (float*)((char*)d_ws + (size_t)GM * GK + (size_t)GN * GK);  // 32 KB

  (void)hipFuncSetAttribute((const void*)gemm_i8,
                            hipFuncAttributeMaxDynamicSharedMemorySize, LDS_BYTES);

  prep_fused_i8<<<PX_BLOCKS + PW_BLOCKS, 256, 0, stream>>>(x, iscale, w, Ai8,
                                                           Wi8, alpha);
  gemm_i8<<<(GM / BM) * (GN / BN), 512, LDS_BYTES, stream>>>(Ai8, Wi8, alpha, out);
  ln_fuse<<<GM, 256, 0, stream>>>(out, oscale, bias, gamma, beta);
}

// Round 21
// 212.986 us; speedup vs baseline: 1.0304x; 1.0304x over previous
//
#include <hip/hip_runtime.h>
#include <hip/hip_bf16.h>

// Problem constants (fixed by reference): B=4, S=2048, DIN=DOUT=4096
constexpr int GM = 8192;   // B*S rows
constexpr int GN = 4096;   // DOUT
constexpr int GK = 4096;   // DIN

constexpr int BM = 256, BN = 256, BK = 64;    // BK in i8 elements (= bytes)
constexpr int NSTEP = GK / BK;                // 64 K-steps
constexpr int SLOT_BYTES = (BM + BN) * BK;    // 32768 (A 16K + B 16K, i8)
constexpr int LDS_BYTES = 2 * SLOT_BYTES;     // 65536

constexpr int PX_BLOCKS = GM;                          // 8192 (1 block/row)
constexpr int PW_BLOCKS = (GN * GK) / (256 * 8);       // 8192

using bf16x8 = __attribute__((ext_vector_type(8))) __bf16;
using i32x4  = __attribute__((ext_vector_type(4))) int;

// ---- fused prep: rows -> per-row absmax i8 quantize; tail -> sign(w) i8 ----
__global__ __launch_bounds__(256) void prep_fused_i8(
    const float* __restrict__ x, const float* __restrict__ iscale,
    const float* __restrict__ w, signed char* __restrict__ A,
    signed char* __restrict__ Wb, float* __restrict__ alpha) {
  int b = blockIdx.x;
  int t = threadIdx.x;
  if (b < PX_BLOCKS) {
    // prep_x: one block per row; alpha[row] = rowmax/127; A = rint(x*s/alpha)
    int row = b;
    const float* xr = x + (size_t)row * GK;
    float v[16];
    float mx = 0.f;
#pragma unroll
    for (int p = 0; p < 4; ++p) {
      int idx = p * 1024 + t * 4;
      float4 xv = *(const float4*)(xr + idx);
      float4 sv = *(const float4*)(iscale + idx);
      float a0 = xv.x * sv.x, a1 = xv.y * sv.y, a2 = xv.z * sv.z, a3 = xv.w * sv.w;
      v[p * 4 + 0] = a0; v[p * 4 + 1] = a1; v[p * 4 + 2] = a2; v[p * 4 + 3] = a3;
      mx = fmaxf(mx, fmaxf(fmaxf(fabsf(a0), fabsf(a1)), fmaxf(fabsf(a2), fabsf(a3))));
    }
#pragma unroll
    for (int off = 32; off > 0; off >>= 1)
      mx = fmaxf(mx, __shfl_down(mx, off));
    __shared__ float rm[4];
    int wid = t >> 6, lane = t & 63;
    if (lane == 0) rm[wid] = mx;
    __syncthreads();
    float m = fmaxf(fmaxf(rm[0], rm[1]), fmaxf(rm[2], rm[3]));
    float inv = m > 0.f ? 127.f / m : 0.f;
    if (t == 0) alpha[row] = m * (1.f / 127.f);
#pragma unroll
    for (int p = 0; p < 4; ++p) {
      int idx = p * 1024 + t * 4;
      char4 q;
      int q0 = (int)rintf(v[p * 4 + 0] * inv);
      int q1 = (int)rintf(v[p * 4 + 1] * inv);
      int q2 = (int)rintf(v[p * 4 + 2] * inv);
      int q3 = (int)rintf(v[p * 4 + 3] * inv);
      q.x = (signed char)max(-127, min(127, q0));
      q.y = (signed char)max(-127, min(127, q1));
      q.z = (signed char)max(-127, min(127, q2));
      q.w = (signed char)max(-127, min(127, q3));
      *(char4*)(A + (size_t)row * GK + idx) = q;
    }
  } else {
    // prep_w: sign(w) in {-1,0,+1}, exact
    int e = ((b - PX_BLOCKS) * 256 + t) * 8;
    float4 v0 = *(const float4*)(w + e);
    float4 v1 = *(const float4*)(w + e + 4);
    auto sg = [](float v) -> signed char {
      return (signed char)((v > 0.f) - (v < 0.f));
    };
    union { signed char c[8]; unsigned long long u; } o;
    o.c[0] = sg(v0.x); o.c[1] = sg(v0.y); o.c[2] = sg(v0.z); o.c[3] = sg(v0.w);
    o.c[4] = sg(v1.x); o.c[5] = sg(v1.y); o.c[6] = sg(v1.z); o.c[7] = sg(v1.w);
    *(unsigned long long*)(Wb + e) = o.u;
  }
}

// -------------------- GEMM (i8): C[m][n] = alpha_m * sum_k qA[m][k]*sgnW[n][k] ----
// R19 (best: zero-asm m97-shaped loop, 16x16x64 i8, 0 conflicts) + two
// changes:
// 1) ANTI-PHASE STAGGER: per-CU accounting shows the two co-resident
//    blocks are PHASE-LOCKED: measured round (both blocks advance one
//    K-step) = 5212 cyc ~= serial sum of pipe work (MFMA 2613 + LDS 2812)
//    — both blocks read LDS together, then MFMA together. They launch
//    simultaneously (512 blocks = exactly 2 dispatch waves; co-resident
//    pair = (b, b+256), same XCD since (b+256)&7 = b&7), run identical
//    code, zero relative drift -> initial phase persists. s_sleep(24)
//    (~1536 cyc ~ half a phase) for the second dispatch wave starts the
//    pair anti-phased: block A's reads run while B MFMAs. Anti-phase is
//    self-sustaining (equal step durations). Pure delay; no correctness
//    impact. Expected round -> ~max(LDS, MFMA) + eps.
// 2) bf-FIRST READ ORDER: the MFMA loop consumes af[0] x bf[0..3] first;
//    reading bf[0..3] before af[0..7] lets the first MFMA issue after 5
//    landed reads (was 9) — the compiler's counted lgkmcnt drains the
//    remaining ~7 reads UNDER the MFMA stream.
// Rest identical to R19: per K-step { STAGE(t+1 -> buf^1); plain-C++
// ds_reads; 32 MFMA; __syncthreads() } — the compiler-inserted full drain
// before s_barrier provides stage visibility + WAR; the stage was issued
// a full K-step (~2300 cyc >> 900-cyc HBM) earlier. Swizzle (0 conflicts
// R17-R19): 16-B chunk c of row r holds k-group c^((r>>1)&3), both sides.
// i8 16x16x64 fragment: row/col = l&15, k = (l>>4)*16 + e; C/D layout:
// col = lane&15, row = (lane>>4)*4 + r. Epilogue: h = alpha[row]*acc ->
// bf16 into 2nd half of each f32 row slot.
__device__ inline void gload16(const void* g, const void* l) {
  __builtin_amdgcn_global_load_lds(
      (const __attribute__((address_space(1))) void*)g,
      (__attribute__((address_space(3))) void*)l, 16, 0, 0);
}

__global__ __launch_bounds__(512, 2) void gemm_i8(
    const signed char* __restrict__ A, const signed char* __restrict__ Bm,
    const float* __restrict__ alpha, float* __restrict__ C) {
  extern __shared__ signed char lds8[];  // 2 slots x (A 16K + B 16K)

  // anti-phase stagger for the second dispatch wave (co-resident partner)
  if (blockIdx.x & 256) __builtin_amdgcn_s_sleep(24);

  // Square XCD chunking (R3-R19; FETCH ~98 MB on i8)
  int bid = blockIdx.x;            // 0..511
  int x = bid & 7, idx = bid >> 3;
  int brow = ((x & 3) << 3) | (idx & 7);   // 0..31
  int bcol = ((x >> 2) << 3) | (idx >> 3); // 0..15

  int tid = threadIdx.x, wid = tid >> 6, lane = tid & 63;
  int wm = wid & 1, wn = wid >> 1;         // 2M x 4N waves
  int lrow = lane & 15, lkhi = lane >> 4;

  const signed char* Ab = A + (size_t)(brow * BM) * GK;
  const signed char* Bb = Bm + (size_t)(bcol * BN) * GK;

  // read-side swizzled chunk (4 x 16-B chunks per 64-B row)
  int rchunk = lkhi ^ ((lrow >> 1) & 3);
  int avbase = (wm * 128 + lrow) * 64 + rchunk * 16;          // + mi*1024
  int bvbase = 16384 + (wn * 64 + lrow) * 64 + rchunk * 16;   // + ni*1024

  // stage-side: thread t covers row t>>2 (0..127), chunk t&3; source chunk
  // pre-permuted so LDS chunk c of row r holds k-group c^((r>>1)&3).
  // Row+128 (2nd issue) preserves (r>>1)&3, so the same gcol applies.
  int grow = tid >> 2;
  int gcol = ((tid & 3) ^ ((tid >> 3) & 3)) * 16;  // byte offset in 64-B window

  auto STAGE = [&](int kstep, int si) {
    const signed char* sA = Ab + (size_t)grow * GK + kstep * BK + gcol;
    const signed char* dA = lds8 + si * SLOT_BYTES + tid * 16;
    gload16(sA, dA);
    gload16(sA + (size_t)128 * GK, dA + 8192);
    const signed char* sB = Bb + (size_t)grow * GK + kstep * BK + gcol;
    gload16(sB, dA + 16384);
    gload16(sB + (size_t)128 * GK, dA + 16384 + 8192);
  };

  i32x4 acc[8][4] = {};

  // prologue: step 0 -> slot 0 (syncthreads drains vmcnt before the barrier)
  STAGE(0, 0);
  __syncthreads();

  for (int t = 0; t < NSTEP; ++t) {
    const signed char* sl = lds8 + (t & 1) * SLOT_BYTES;
    if (t + 1 < NSTEP) STAGE(t + 1, (t + 1) & 1);

    // plain C++ LDS reads, bf FIRST so the first MFMA's operands land
    // earliest; compiler emits counted lgkmcnt and interleaves the MFMAs
    // below with the remaining in-flight reads.
    i32x4 af[8], bf[4];
#pragma unroll
    for (int ni = 0; ni < 4; ++ni)
      bf[ni] = *(const i32x4*)(sl + bvbase + ni * 1024);
#pragma unroll
    for (int mi = 0; mi < 8; ++mi)
      af[mi] = *(const i32x4*)(sl + avbase + mi * 1024);

#pragma unroll
    for (int mi = 0; mi < 8; ++mi)
#pragma unroll
      for (int ni = 0; ni < 4; ++ni)
        acc[mi][ni] = __builtin_amdgcn_mfma_i32_16x16x64_i8(
            af[mi], bf[ni], acc[mi][ni], 0, 0, 0);

    // one barrier per K-step: makes STAGE(t+1) visible for step t+1 and
    // orders this step's reads before STAGE(t+2)'s overwrite (WAR).
    __syncthreads();
  }

  // epilogue: h = alpha[row]*acc as bf16 into 2nd half of each f32 row slot.
  // C/D layout: col = lane&15, row = (lane>>4)*4 + r
  int crow0 = brow * BM + wm * 128;
  int ccol0 = bcol * BN + wn * 64;
  char* Cb = (char*)C;
#pragma unroll
  for (int mi = 0; mi < 8; ++mi)
#pragma unroll
    for (int ni = 0; ni < 4; ++ni) {
      int col = ccol0 + ni * 16 + lrow;
#pragma unroll
      for (int r = 0; r < 4; ++r) {
        int row = crow0 + mi * 16 + lkhi * 4 + r;
        float h = alpha[row] * (float)acc[mi][ni][r];
        *(__bf16*)(Cb + (size_t)row * 16384 + 8192 + col * 2) = (__bf16)h;
      }
    }
}

// ---------- fused out_scale/bias + LayerNorm: bf16 h (2nd half-slot) -> f32 ----------
__global__ __launch_bounds__(256) void ln_fuse(
    float* __restrict__ out, const float* __restrict__ os,
    const float* __restrict__ bs, const float* __restrict__ g,
    const float* __restrict__ be) {
  constexpr int N = GN;  // 4096
  int row = blockIdx.x;
  const __bf16* hr = (const __bf16*)((const char*)out + (size_t)row * 16384 + 8192);
  float* orow = out + (size_t)row * N;
  int t = threadIdx.x;

  float v[16];
  float sum = 0.f, ssq = 0.f;
#pragma unroll
  for (int c = 0; c < 2; ++c) {
    int idx = c * 2048 + t * 8;       // 8 bf16 per chunk, 2 chunks/thread
    bf16x8 hv = *(const bf16x8*)(hr + idx);
    float4 s0 = *(const float4*)(os + idx);
    float4 s1 = *(const float4*)(os + idx + 4);
    float4 b0 = *(const float4*)(bs + idx);
    float4 b1 = *(const float4*)(bs + idx + 4);
#pragma unroll
    for (int j = 0; j < 4; ++j) {
      float a = (float)hv[j] * (&s0.x)[j] + (&b0.x)[j];
      v[c * 8 + j] = a;
      sum += a; ssq += a * a;
    }
#pragma unroll
    for (int j = 0; j < 4; ++j) {
      float a = (float)hv[4 + j] * (&s1.x)[j] + (&b1.x)[j];
      v[c * 8 + 4 + j] = a;
      sum += a; ssq += a * a;
    }
  }

  // wave64 reduce
#pragma unroll
  for (int off = 32; off > 0; off >>= 1) {
    sum += __shfl_down(sum, off);
    ssq += __shfl_down(ssq, off);
  }
  __shared__ float rs[8];
  int wid = t >> 6, lane = t & 63;
  if (lane == 0) { rs[wid] = sum; rs[4 + wid] = ssq; }
  __syncthreads();   // also separates all h reads from the in-place writes
  sum = rs[0] + rs[1] + rs[2] + rs[3];
  ssq = rs[4] + rs[5] + rs[6] + rs[7];

  float mean = sum * (1.f / N);
  float var = ssq * (1.f / N) - mean * mean;
  float rstd = rsqrtf(var + 1e-5f);

#pragma unroll
  for (int c = 0; c < 2; ++c) {
    int idx = c * 2048 + t * 8;
    float4 g0 = *(const float4*)(g + idx);
    float4 g1 = *(const float4*)(g + idx + 4);
    float4 e0 = *(const float4*)(be + idx);
    float4 e1 = *(const float4*)(be + idx + 4);
    float4 o0, o1;
#pragma unroll
    for (int j = 0; j < 4; ++j) {
      (&o0.x)[j] = (v[c * 8 + j] - mean) * rstd * (&g0.x)[j] + (&e0.x)[j];
      (&o1.x)[j] = (v[c * 8 + 4 + j] - mean) * rstd * (&g1.x)[j] + (&e1.x)[j];
    }
    *(float4*)(orow + idx) = o0;
    *(float4*)(orow + idx + 4) = o1;
  }
}

extern "C" void kernel_launch(void* const* d_in, const int* in_sizes, int n_in,
                              void* d_out, int out_size, void* d_ws, size_t ws_size,
                              hipStream_t stream) {
  const float* x      = (const float*)d_in[0];  // [4,2048,4096]
  const float* w      = (const float*)d_in[1];  // [4096,4096]
  const float* iscale = (const float*)d_in[2];  // [4096]
  const float* oscale = (const float*)d_in[3];  // [4096]
  const float* bias   = (const float*)d_in[4];  // [4096]
  const float* gamma  = (const float*)d_in[5];  // [4096]
  const float* beta   = (const float*)d_in[6];  // [4096]
  float* out = (float*)d_out;                   // [8192,4096] f32

  signed char* Ai8 = (signed char*)d_ws;                         // 33.6 MB
  signed char* Wi8 = (signed char*)d_ws + (size_t)GM * GK;       // 16.8 MB
  float* alpha = (float*)((char*)d_ws + (size_t)GM * GK + (size_t)GN * GK);  // 32 KB

  (void)hipFuncSetAttribute((const void*)gemm_i8,
                            hipFuncAttributeMaxDynamicSharedMemorySize, LDS_BYTES);

  prep_fused_i8<<<PX_BLOCKS + PW_BLOCKS, 256, 0, stream>>>(x, iscale, w, Ai8,
                                                           Wi8, alpha);
  gemm_i8<<<(GM / BM) * (GN / BN), 512, LDS_BYTES, stream>>>(Ai8, Wi8, alpha, out);
  ln_fuse<<<GM, 256, 0, stream>>>(out, oscale, bias, gamma, beta);
}